// Round 1
// baseline (523.407 us; speedup 1.0000x reference)
//
#include <hip/hip_runtime.h>
#include <math.h>

#define B_ 4
#define T_ 4096
#define C_ 2048
#define HD_ 128
#define M_ (B_*T_)   // 16384 rows total

typedef __bf16 bf8 __attribute__((ext_vector_type(8)));
typedef unsigned short u16x8 __attribute__((ext_vector_type(8)));
typedef float f32x4 __attribute__((ext_vector_type(4)));

__device__ inline unsigned short f2bf(float f) {
    unsigned u = __builtin_bit_cast(unsigned, f);
    u += 0x7FFFu + ((u >> 16) & 1u);   // round-to-nearest-even
    return (unsigned short)(u >> 16);
}
__device__ inline float bf2f(unsigned short h) {
    unsigned u = ((unsigned)h) << 16;
    return __builtin_bit_cast(float, u);
}
__device__ inline bf8 ld_bf8(const unsigned short* p) {
    u16x8 t = *(const u16x8*)p;
    return __builtin_bit_cast(bf8, t);
}
__device__ inline f32x4 zero4() { f32x4 v = {0.f, 0.f, 0.f, 0.f}; return v; }

// ---------------------------------------------------------------------------
// Kernel 1: q/k/v = x @ {Wq,Wk,Wv}^T  (bf16 MFMA), fused interleaved RoPE on
// q,k. Writes bf16: qws[row][d], kws[row][d], vws[b][d][t] (v transposed so
// attention PV B-fragments are contiguous).
// Grid: 256 blocks x 256 thr. Block = 64 rows x 384 cols, K-chunks of 64.
// ---------------------------------------------------------------------------
__global__ __launch_bounds__(256) void qkv_rope_kernel(
    const float* __restrict__ x,  const float* __restrict__ Wq,
    const float* __restrict__ Wk, const float* __restrict__ Wv,
    const float* __restrict__ cosp, const float* __restrict__ sinp,
    unsigned short* __restrict__ qws, unsigned short* __restrict__ kws,
    unsigned short* __restrict__ vws)
{
    __shared__ __align__(16) unsigned short xs[64][72];    // 64 rows x 64 k (+8 pad)
    __shared__ __align__(16) unsigned short wsh[384][72];  // 384 w-rows x 64 k (+8 pad)

    const int tid = threadIdx.x;
    const int w = tid >> 6, l = tid & 63;
    const int rowbase = blockIdx.x * 64;

    f32x4 acc[24];
    #pragma unroll
    for (int i = 0; i < 24; ++i) acc[i] = zero4();

    const int sr = tid >> 2;          // staging row 0..63
    const int sc = (tid & 3) << 4;    // staging col 0/16/32/48

    const int am = w * 16 + (l & 15); // A-frag m row (wave-local tile)
    const int ak = (l >> 4) * 8;      // A/B-frag k offset
    const int coll = l & 15;

    for (int kc = 0; kc < C_; kc += 64) {
        __syncthreads();
        // stage x tile (fp32 -> bf16)
        {
            const float* xp = x + (size_t)(rowbase + sr) * C_ + kc + sc;
            #pragma unroll
            for (int i = 0; i < 16; i += 4) {
                float4 v = *(const float4*)(xp + i);
                xs[sr][sc + i + 0] = f2bf(v.x);
                xs[sr][sc + i + 1] = f2bf(v.y);
                xs[sr][sc + i + 2] = f2bf(v.z);
                xs[sr][sc + i + 3] = f2bf(v.w);
            }
        }
        // stage W tile: rows 0..127 = Wq, 128..255 = Wk, 256..383 = Wv
        #pragma unroll
        for (int p = 0; p < 6; ++p) {
            int wr = p * 64 + sr;
            const float* wp = (wr < 128 ? Wq + (size_t)wr * C_
                             : wr < 256 ? Wk + (size_t)(wr - 128) * C_
                                        : Wv + (size_t)(wr - 256) * C_) + kc + sc;
            #pragma unroll
            for (int i = 0; i < 16; i += 4) {
                float4 v = *(const float4*)(wp + i);
                wsh[wr][sc + i + 0] = f2bf(v.x);
                wsh[wr][sc + i + 1] = f2bf(v.y);
                wsh[wr][sc + i + 2] = f2bf(v.z);
                wsh[wr][sc + i + 3] = f2bf(v.w);
            }
        }
        __syncthreads();
        // MFMA: 2 k-steps x 24 n-tiles
        #pragma unroll
        for (int ks = 0; ks < 2; ++ks) {
            bf8 a = ld_bf8(&xs[am][ks * 32 + ak]);
            #pragma unroll
            for (int nt = 0; nt < 24; ++nt) {
                bf8 b = ld_bf8(&wsh[nt * 16 + coll][ks * 32 + ak]);
                acc[nt] = __builtin_amdgcn_mfma_f32_16x16x32_bf16(a, b, acc[nt], 0, 0, 0);
            }
        }
    }

    // Epilogue: RoPE on q,k (interleaved pairs via shfl_xor(1)), store bf16.
    const int rloc = w * 16 + ((l >> 4) << 2);
    #pragma unroll
    for (int nt = 0; nt < 24; ++nt) {
        int col = nt * 16 + coll;
        #pragma unroll
        for (int r = 0; r < 4; ++r) {
            float val = acc[nt][r];
            int grow = rowbase + rloc + r;
            int t = grow & (T_ - 1);
            if (nt < 16) {
                float other = __shfl_xor(val, 1, 64);
                int hc = col & 127;        // head col 0..127
                int i = hc >> 1;           // rope pair index
                float cv = cosp[t * 64 + i];
                float sv = sinp[t * 64 + i];
                // even: vr*c - vi*s ; odd: vr*s + vi*c
                float outv = (hc & 1) ? (val * cv + other * sv)
                                      : (val * cv - other * sv);
                if (nt < 8) qws[(size_t)grow * HD_ + hc] = f2bf(outv);
                else        kws[(size_t)grow * HD_ + hc] = f2bf(outv);
            } else {
                int d = col - 256;
                int b = grow >> 12;
                vws[((size_t)(b * HD_ + d)) * T_ + t] = f2bf(val);
            }
        }
    }
}

// ---------------------------------------------------------------------------
// Kernel 2: causal flash attention. Grid: B*64 blocks (one 64-row Q tile),
// 256 thr (4 waves x 16 q-rows). Online softmax, fp32 stats, bf16 MFMA.
// P goes through LDS (C-layout -> A-layout).
// ---------------------------------------------------------------------------
__global__ __launch_bounds__(256) void attn_kernel(
    const unsigned short* __restrict__ qws, const unsigned short* __restrict__ kws,
    const unsigned short* __restrict__ vws, float* __restrict__ out)
{
    __shared__ __align__(16) unsigned short qs[64][136];  // 64 x 128 (+8)
    __shared__ __align__(16) unsigned short ks[64][136];
    __shared__ __align__(16) unsigned short vs[128][72];  // transposed: [d][s]
    __shared__ __align__(16) unsigned short ps[64][72];   // P tile

    const int tid = threadIdx.x;
    const int w = tid >> 6, l = tid & 63;
    const int b  = blockIdx.x >> 6;
    const int qt = blockIdx.x & 63;
    const int qbase = qt * 64;
    const size_t rowoff = (size_t)b * T_;

    const int am = w * 16 + (l & 15);
    const int ak = (l >> 4) * 8;
    const int coll = l & 15;
    const int rloc = (l >> 4) << 2;

    // load Q tile once
    {
        int r = tid >> 2;
        int c0 = (tid & 3) * 32;
        const unsigned short* qp = qws + (rowoff + qbase + r) * HD_ + c0;
        *(u16x8*)&qs[r][c0 + 0]  = *(const u16x8*)(qp + 0);
        *(u16x8*)&qs[r][c0 + 8]  = *(const u16x8*)(qp + 8);
        *(u16x8*)&qs[r][c0 + 16] = *(const u16x8*)(qp + 16);
        *(u16x8*)&qs[r][c0 + 24] = *(const u16x8*)(qp + 24);
    }

    float m_r[4] = {-1e30f, -1e30f, -1e30f, -1e30f};
    float l_r[4] = {0.f, 0.f, 0.f, 0.f};
    f32x4 accO[8];
    #pragma unroll
    for (int i = 0; i < 8; ++i) accO[i] = zero4();

    const float scale = 0.022097086912079608f;  // C^-0.5 = 1/sqrt(2048)

    for (int st = 0; st <= qt; ++st) {
        const int sbase = st * 64;
        __syncthreads();   // prior-iteration readers done
        // stage K tile
        {
            int r = tid >> 2;
            int c0 = (tid & 3) * 32;
            const unsigned short* kp = kws + (rowoff + sbase + r) * HD_ + c0;
            *(u16x8*)&ks[r][c0 + 0]  = *(const u16x8*)(kp + 0);
            *(u16x8*)&ks[r][c0 + 8]  = *(const u16x8*)(kp + 8);
            *(u16x8*)&ks[r][c0 + 16] = *(const u16x8*)(kp + 16);
            *(u16x8*)&ks[r][c0 + 24] = *(const u16x8*)(kp + 24);
        }
        // stage V tile (already transposed in global: vws[b][d][t])
        {
            int d = tid >> 1;
            int s0 = (tid & 1) * 32;
            const unsigned short* vp = vws + ((size_t)(b * HD_ + d)) * T_ + sbase + s0;
            *(u16x8*)&vs[d][s0 + 0]  = *(const u16x8*)(vp + 0);
            *(u16x8*)&vs[d][s0 + 8]  = *(const u16x8*)(vp + 8);
            *(u16x8*)&vs[d][s0 + 16] = *(const u16x8*)(vp + 16);
            *(u16x8*)&vs[d][s0 + 24] = *(const u16x8*)(vp + 24);
        }
        __syncthreads();

        // S = Q K^T (16 q-rows per wave x 64 k-cols)
        f32x4 sacc[4];
        #pragma unroll
        for (int i = 0; i < 4; ++i) sacc[i] = zero4();
        #pragma unroll
        for (int kk = 0; kk < 4; ++kk) {
            bf8 a = ld_bf8(&qs[am][kk * 32 + ak]);
            #pragma unroll
            for (int nt = 0; nt < 4; ++nt) {
                bf8 bb = ld_bf8(&ks[nt * 16 + coll][kk * 32 + ak]);
                sacc[nt] = __builtin_amdgcn_mfma_f32_16x16x32_bf16(a, bb, sacc[nt], 0, 0, 0);
            }
        }

        // scale + causal mask + online softmax update
        #pragma unroll
        for (int r = 0; r < 4; ++r) {
            int qi = qbase + w * 16 + rloc + r;
            float mx = -1e30f;
            float pv[4];
            #pragma unroll
            for (int nt = 0; nt < 4; ++nt) {
                int ki = sbase + nt * 16 + coll;
                float sv = sacc[nt][r] * scale;
                if (ki > qi) sv = -1e30f;
                pv[nt] = sv;
                mx = fmaxf(mx, sv);
            }
            mx = fmaxf(mx, __shfl_xor(mx, 1, 64));
            mx = fmaxf(mx, __shfl_xor(mx, 2, 64));
            mx = fmaxf(mx, __shfl_xor(mx, 4, 64));
            mx = fmaxf(mx, __shfl_xor(mx, 8, 64));
            float mnew = fmaxf(m_r[r], mx);
            float sum = 0.f;
            #pragma unroll
            for (int nt = 0; nt < 4; ++nt) {
                float p = __expf(pv[nt] - mnew);
                unsigned short pb = f2bf(p);
                ps[w * 16 + rloc + r][nt * 16 + coll] = pb;
                sum += bf2f(pb);   // denominator consistent with bf16 numerator
            }
            sum += __shfl_xor(sum, 1, 64);
            sum += __shfl_xor(sum, 2, 64);
            sum += __shfl_xor(sum, 4, 64);
            sum += __shfl_xor(sum, 8, 64);
            float alpha = __expf(m_r[r] - mnew);
            l_r[r] = l_r[r] * alpha + sum;
            m_r[r] = mnew;
            #pragma unroll
            for (int nt = 0; nt < 8; ++nt) accO[nt][r] *= alpha;
        }
        __syncthreads();   // ps visible (and uniform schedule)

        // O += P V
        #pragma unroll
        for (int kk = 0; kk < 2; ++kk) {
            bf8 a = ld_bf8(&ps[am][kk * 32 + ak]);
            #pragma unroll
            for (int nt = 0; nt < 8; ++nt) {
                bf8 bb = ld_bf8(&vs[nt * 16 + coll][kk * 32 + ak]);
                accO[nt] = __builtin_amdgcn_mfma_f32_16x16x32_bf16(a, bb, accO[nt], 0, 0, 0);
            }
        }
    }

    // epilogue: out = O / l  (fp32)
    #pragma unroll
    for (int r = 0; r < 4; ++r) {
        float inv = 1.f / l_r[r];
        int grow = b * T_ + qbase + w * 16 + rloc + r;
        #pragma unroll
        for (int nt = 0; nt < 8; ++nt) {
            out[(size_t)grow * HD_ + nt * 16 + coll] = accO[nt][r] * inv;
        }
    }
}

extern "C" void kernel_launch(void* const* d_in, const int* in_sizes, int n_in,
                              void* d_out, int out_size, void* d_ws, size_t ws_size,
                              hipStream_t stream) {
    const float* x    = (const float*)d_in[0];
    const float* Wq   = (const float*)d_in[1];
    const float* Wk   = (const float*)d_in[2];
    const float* Wv   = (const float*)d_in[3];
    const float* cosp = (const float*)d_in[4];
    const float* sinp = (const float*)d_in[5];
    float* out = (float*)d_out;

    unsigned short* qws = (unsigned short*)d_ws;              // 16384*128 bf16
    unsigned short* kws = qws + (size_t)M_ * HD_;
    unsigned short* vws = kws + (size_t)M_ * HD_;             // (B,128,T) bf16

    qkv_rope_kernel<<<dim3(M_ / 64), dim3(256), 0, stream>>>(
        x, Wq, Wk, Wv, cosp, sinp, qws, kws, vws);
    attn_kernel<<<dim3(B_ * (T_ / 64)), dim3(256), 0, stream>>>(
        qws, kws, vws, out);
}

// Round 2
// 359.410 us; speedup vs baseline: 1.4563x; 1.4563x over previous
//
#include <hip/hip_runtime.h>

#define B_ 4
#define T_ 4096
#define C_ 2048
#define HD_ 128
#define M_ (B_*T_)   // 16384 rows total

typedef __bf16 bf8 __attribute__((ext_vector_type(8)));
typedef unsigned short u16x8 __attribute__((ext_vector_type(8)));
typedef unsigned short u16x4 __attribute__((ext_vector_type(4)));
typedef float f32x4 __attribute__((ext_vector_type(4)));

typedef __attribute__((address_space(3))) unsigned char lds_u8_t;
typedef __attribute__((address_space(1))) const unsigned char gm_u8_t;

// async global->LDS, 16B per lane; LDS dest = wave-uniform base + lane*16
__device__ __forceinline__ void glds16(const void* g, void* l) {
    __builtin_amdgcn_global_load_lds((gm_u8_t*)g, (lds_u8_t*)l, 16, 0, 0);
}

__device__ __forceinline__ unsigned short f2bf(float f) {
    unsigned u = __builtin_bit_cast(unsigned, f);
    u += 0x7FFFu + ((u >> 16) & 1u);   // RNE
    return (unsigned short)(u >> 16);
}
__device__ __forceinline__ float bf2f(unsigned short h) {
    unsigned u = ((unsigned)h) << 16;
    return __builtin_bit_cast(float, u);
}
__device__ __forceinline__ bf8 ld_bf8(const unsigned short* p) {
    u16x8 t = *(const u16x8*)p;
    return __builtin_bit_cast(bf8, t);
}
__device__ __forceinline__ f32x4 zero4() { f32x4 v = {0.f,0.f,0.f,0.f}; return v; }

// ---------------------------------------------------------------------------
// Kernel 0: convert Wq|Wk|Wv (fp32) -> wbf (bf16), contiguous [3][128][2048]
// ---------------------------------------------------------------------------
__global__ __launch_bounds__(256) void wconv(
    const float* __restrict__ Wq, const float* __restrict__ Wk,
    const float* __restrict__ Wv, unsigned short* __restrict__ wbf)
{
    int idx = blockIdx.x * 256 + threadIdx.x;   // 0..98303
    int e = idx * 8;
    int z = e >> 18;                            // 128*2048 = 262144 = 2^18
    int r = e & 262143;
    const float* src = (z == 0 ? Wq : z == 1 ? Wk : Wv) + r;
    float4 a = *(const float4*)src;
    float4 b = *(const float4*)(src + 4);
    u16x8 o;
    o[0]=f2bf(a.x); o[1]=f2bf(a.y); o[2]=f2bf(a.z); o[3]=f2bf(a.w);
    o[4]=f2bf(b.x); o[5]=f2bf(b.y); o[6]=f2bf(b.z); o[7]=f2bf(b.w);
    *(u16x8*)(wbf + e) = o;
}

// ---------------------------------------------------------------------------
// Kernel 1: per-matrix GEMM (x @ Wz^T) + RoPE epilogue.
// grid 768 = 256 m-tiles x 3 matrices; block 256 thr; tile 64 rows x 128 cols,
// BK=64. x staged as raw fp32 via global_load_lds (bf16 cvt at frag build),
// W staged bf16. XOR slot swizzle (slot ^ (row&7)) for conflict-free ds_read.
// Wave tiling 2x2: wave w -> rows (w&1)*32+mi*16, cols (w>>1)*64+nt*16.
// ---------------------------------------------------------------------------
__global__ __launch_bounds__(256) void qkv_gemm(
    const float* __restrict__ x, const unsigned short* __restrict__ wbf,
    const float* __restrict__ cosp, const float* __restrict__ sinp,
    unsigned short* __restrict__ qws, unsigned short* __restrict__ kws,
    unsigned short* __restrict__ vws)
{
    __shared__ __align__(16) float xs[64*64];            // 16 KB, [row][64 f32]
    __shared__ __align__(16) unsigned short ws2[128*64]; // 16 KB, [row][64 bf16]

    const int tid = threadIdx.x;
    const int w = tid >> 6, l = tid & 63;
    const int mt = blockIdx.x / 3, z = blockIdx.x - mt * 3;
    const int rowbase = mt * 64;

    const int swz = l & 7;
    const int aq  = l >> 4;
    const int coll = l & 15;

    f32x4 acc[2][4];
    #pragma unroll
    for (int i = 0; i < 2; ++i)
        #pragma unroll
        for (int j = 0; j < 4; ++j) acc[i][j] = zero4();

    const unsigned short* wsrc = wbf + (size_t)z * (HD_ * C_);

    for (int kc = 0; kc < C_; kc += 64) {
        __syncthreads();
        // stage x tile: 64 rows x 64 f32 (16 calls, 4/wave), fetch swizzled
        #pragma unroll
        for (int c = 0; c < 4; ++c) {
            int row = w * 16 + c * 4 + aq;
            int fb = coll ^ (row & 7);
            glds16(x + (size_t)(rowbase + row) * C_ + kc + fb * 4,
                   (void*)&xs[(w * 16 + c * 4) * 64]);
        }
        // stage W tile: 128 rows x 64 bf16 (16 calls, 4/wave)
        #pragma unroll
        for (int c = 0; c < 4; ++c) {
            int row = w * 32 + c * 8 + (l >> 3);
            int fb = (l & 7) ^ (row & 7);
            glds16(wsrc + (size_t)row * C_ + kc + fb * 8,
                   (void*)&ws2[(w * 32 + c * 8) * 64]);
        }
        __syncthreads();

        #pragma unroll
        for (int ks_ = 0; ks_ < 2; ++ks_) {
            bf8 a[2];
            #pragma unroll
            for (int mi = 0; mi < 2; ++mi) {
                int row = (w & 1) * 32 + mi * 16 + coll;   // row&7 == swz
                int s0 = ks_ * 8 + aq * 2;
                float4 fa = *(const float4*)&xs[row * 64 + ((s0 ^ swz) << 2)];
                float4 fb = *(const float4*)&xs[row * 64 + (((s0 + 1) ^ swz) << 2)];
                u16x8 t;
                t[0]=f2bf(fa.x); t[1]=f2bf(fa.y); t[2]=f2bf(fa.z); t[3]=f2bf(fa.w);
                t[4]=f2bf(fb.x); t[5]=f2bf(fb.y); t[6]=f2bf(fb.z); t[7]=f2bf(fb.w);
                a[mi] = __builtin_bit_cast(bf8, t);
            }
            #pragma unroll
            for (int nt = 0; nt < 4; ++nt) {
                int row = (w >> 1) * 64 + nt * 16 + coll;  // row&7 == swz
                int slot = (ks_ * 4 + aq) ^ swz;
                bf8 bb = ld_bf8(&ws2[row * 64 + (slot << 3)]);
                acc[0][nt] = __builtin_amdgcn_mfma_f32_16x16x32_bf16(a[0], bb, acc[0][nt], 0, 0, 0);
                acc[1][nt] = __builtin_amdgcn_mfma_f32_16x16x32_bf16(a[1], bb, acc[1][nt], 0, 0, 0);
            }
        }
    }

    // epilogue
    const int rl0 = aq * 4;
    const int cbase = (w >> 1) * 64;
    const int mrow = (w & 1) * 32;
    if (z < 2) {
        unsigned short* dst = (z == 0) ? qws : kws;
        #pragma unroll
        for (int mi = 0; mi < 2; ++mi) {
            #pragma unroll
            for (int nt = 0; nt < 4; ++nt) {
                int col = cbase + nt * 16 + coll;
                #pragma unroll
                for (int r = 0; r < 4; ++r) {
                    float val = acc[mi][nt][r];
                    float oth = __shfl_xor(val, 1, 64);
                    int grow = rowbase + mrow + mi * 16 + rl0 + r;
                    int t = grow & (T_ - 1);
                    if ((coll & 1) == 0) {      // even col computes+stores the pair
                        int i = col >> 1;
                        float cv = cosp[t * 64 + i], sv = sinp[t * 64 + i];
                        float o_r = val * cv - oth * sv;
                        float o_i = val * sv + oth * cv;
                        unsigned pack = (unsigned)f2bf(o_r) | ((unsigned)f2bf(o_i) << 16);
                        *(unsigned*)&dst[(size_t)grow * HD_ + col] = pack;
                    }
                }
            }
        }
    } else {
        const int bq = rowbase >> 12;
        #pragma unroll
        for (int mi = 0; mi < 2; ++mi) {
            int tb = (rowbase + mrow + mi * 16 + rl0) & (T_ - 1);
            #pragma unroll
            for (int nt = 0; nt < 4; ++nt) {
                int col = cbase + nt * 16 + coll;
                u16x4 pk;
                pk[0] = f2bf(acc[mi][nt][0]); pk[1] = f2bf(acc[mi][nt][1]);
                pk[2] = f2bf(acc[mi][nt][2]); pk[3] = f2bf(acc[mi][nt][3]);
                *(u16x4*)&vws[(size_t)(bq * HD_ + col) * T_ + tb] = pk;  // transposed
            }
        }
    }
}

// ---------------------------------------------------------------------------
// Kernel 2: causal flash attention. 32-row Q tiles, 64-col K tiles.
// grid 512 (2 blocks/CU), paired scheduling for causal balance.
// Waves: w -> q-rows (w&1)*16, S-cols (w>>1)*32, O-cols (w>>1)*64.
// Cross-wave row stats (pairs w, w^2) via LDS partials. ps aliases ks tail.
// ---------------------------------------------------------------------------
__global__ __launch_bounds__(256) void attn(
    const unsigned short* __restrict__ qws, const unsigned short* __restrict__ kws,
    const unsigned short* __restrict__ vws, float* __restrict__ out)
{
    __shared__ __align__(16) unsigned char smem[41472];
    unsigned short* qs = (unsigned short*)smem;            // [32][128]  8 KB
    unsigned short* ks = (unsigned short*)(smem + 8192);   // [64][128] 16 KB
    unsigned short* vs = (unsigned short*)(smem + 24576);  // [128][64] 16 KB
    float* mpart = (float*)(smem + 40960);                 // [4][16]
    float* lpart = (float*)(smem + 41216);                 // [4][16]
    unsigned short* ps = (unsigned short*)(smem + 19968);  // [32][72], aliases ks rows 46..63

    const int tid = threadIdx.x;
    const int w = tid >> 6, l = tid & 63;
    int idx = blockIdx.x;
    int j = (idx < 256) ? idx : (767 - idx);   // pair (i, i+256) -> complementary depth
    const int b  = j & 3;
    const int qt = j >> 2;                     // 0..127
    const int qbase = qt * 32;
    const size_t rowoff = (size_t)b * T_;

    const int swz = l & 7, aq = l >> 4, coll = l & 15;
    const int rh = (w & 1) * 16;
    const int cg = w >> 1;
    const int rl0 = aq * 4;

    // stage Q once (8 calls, 2/wave)
    #pragma unroll
    for (int c = 0; c < 2; ++c) {
        int row = w * 8 + c * 4 + aq;
        int fb = coll ^ (row & 7);
        glds16(qws + (rowoff + qbase + row) * HD_ + fb * 8,
               (void*)&qs[(w * 8 + c * 4) * 128]);
    }

    float m_r[4] = {-1e30f, -1e30f, -1e30f, -1e30f};
    float l_r[4] = {0.f, 0.f, 0.f, 0.f};
    f32x4 accO[4];
    #pragma unroll
    for (int i = 0; i < 4; ++i) accO[i] = zero4();

    const float scale = 0.022097086912079608f;  // 1/sqrt(2048)
    const int nst = (qt >> 1) + 1;

    for (int st = 0; st < nst; ++st) {
        const int sbase = st * 64;
        __syncthreads();                              // b1: prior PV reads done
        #pragma unroll
        for (int c = 0; c < 4; ++c) {                 // K: 64 rows x 128
            int row = w * 16 + c * 4 + aq;
            int fb = coll ^ (row & 7);
            glds16(kws + (rowoff + sbase + row) * HD_ + fb * 8,
                   (void*)&ks[(w * 16 + c * 4) * 128]);
        }
        #pragma unroll
        for (int c = 0; c < 4; ++c) {                 // V: 128 d-rows x 64 s
            int row = w * 32 + c * 8 + (l >> 3);
            int fb = (l & 7) ^ (row & 7);
            glds16(vws + ((size_t)(b * HD_ + row)) * T_ + sbase + fb * 8,
                   (void*)&vs[(w * 32 + c * 8) * 64]);
        }
        __syncthreads();                              // b2: staging done

        // S = Q K^T (wave: 16 rows x 32 cols)
        f32x4 sacc[2];
        sacc[0] = zero4(); sacc[1] = zero4();
        #pragma unroll
        for (int kk = 0; kk < 4; ++kk) {
            int arow = rh + coll;                     // row&7 == swz
            int slot = (kk * 4 + aq) ^ swz;
            bf8 a = ld_bf8(&qs[arow * 128 + (slot << 3)]);
            #pragma unroll
            for (int nt = 0; nt < 2; ++nt) {
                int brow = cg * 32 + nt * 16 + coll;
                bf8 bb = ld_bf8(&ks[brow * 128 + (slot << 3)]);
                sacc[nt] = __builtin_amdgcn_mfma_f32_16x16x32_bf16(a, bb, sacc[nt], 0, 0, 0);
            }
        }

        // scale + causal mask + wave-partial row max
        float pv[2][4], mw[4];
        #pragma unroll
        for (int r = 0; r < 4; ++r) {
            int qi = qbase + rh + rl0 + r;
            float mx = -1e30f;
            #pragma unroll
            for (int nt = 0; nt < 2; ++nt) {
                int ki = sbase + cg * 32 + nt * 16 + coll;
                float sv = sacc[nt][r] * scale;
                if (ki > qi) sv = -1e30f;
                pv[nt][r] = sv;
                mx = fmaxf(mx, sv);
            }
            mx = fmaxf(mx, __shfl_xor(mx, 1, 64));
            mx = fmaxf(mx, __shfl_xor(mx, 2, 64));
            mx = fmaxf(mx, __shfl_xor(mx, 4, 64));
            mx = fmaxf(mx, __shfl_xor(mx, 8, 64));
            mw[r] = mx;
        }
        if (coll == 0) {
            #pragma unroll
            for (int r = 0; r < 4; ++r) mpart[w * 16 + rl0 + r] = mw[r];
        }
        __syncthreads();                              // b3: mpart ready (+ all ks reads done)

        float lw[4];
        #pragma unroll
        for (int r = 0; r < 4; ++r) {
            float mo = mpart[(w ^ 2) * 16 + rl0 + r];
            float mnew = fmaxf(m_r[r], fmaxf(mw[r], mo));
            float sum = 0.f;
            #pragma unroll
            for (int nt = 0; nt < 2; ++nt) {
                float p = __expf(pv[nt][r] - mnew);
                unsigned short pb = f2bf(p);
                ps[(rh + rl0 + r) * 72 + cg * 32 + nt * 16 + coll] = pb;
                sum += bf2f(pb);                      // denom consistent with bf16 numer
            }
            sum += __shfl_xor(sum, 1, 64);
            sum += __shfl_xor(sum, 2, 64);
            sum += __shfl_xor(sum, 4, 64);
            sum += __shfl_xor(sum, 8, 64);
            lw[r] = sum;
            mw[r] = mnew;                             // carry mnew
        }
        if (coll == 0) {
            #pragma unroll
            for (int r = 0; r < 4; ++r) lpart[w * 16 + rl0 + r] = lw[r];
        }
        __syncthreads();                              // b4: lpart + ps ready

        #pragma unroll
        for (int r = 0; r < 4; ++r) {
            float lo = lpart[(w ^ 2) * 16 + rl0 + r];
            float mnew = mw[r];
            float alpha = __expf(m_r[r] - mnew);
            l_r[r] = l_r[r] * alpha + lw[r] + lo;
            m_r[r] = mnew;
            #pragma unroll
            for (int nt = 0; nt < 4; ++nt) accO[nt][r] *= alpha;
        }

        // O += P V (wave: 16 rows x 64 O-cols)
        #pragma unroll
        for (int kk = 0; kk < 2; ++kk) {
            bf8 a = ld_bf8(&ps[(rh + coll) * 72 + kk * 32 + aq * 8]);
            #pragma unroll
            for (int nt = 0; nt < 4; ++nt) {
                int brow = cg * 64 + nt * 16 + coll;
                int slot = (kk * 4 + aq) ^ swz;
                bf8 bb = ld_bf8(&vs[brow * 64 + (slot << 3)]);
                accO[nt] = __builtin_amdgcn_mfma_f32_16x16x32_bf16(a, bb, accO[nt], 0, 0, 0);
            }
        }
    }

    // epilogue: out = O / l
    #pragma unroll
    for (int r = 0; r < 4; ++r) {
        float inv = 1.f / l_r[r];
        int grow = qbase + rh + rl0 + r;
        #pragma unroll
        for (int nt = 0; nt < 4; ++nt) {
            int col = cg * 64 + nt * 16 + coll;
            out[(rowoff + grow) * HD_ + col] = accO[nt][r] * inv;
        }
    }
}

extern "C" void kernel_launch(void* const* d_in, const int* in_sizes, int n_in,
                              void* d_out, int out_size, void* d_ws, size_t ws_size,
                              hipStream_t stream) {
    const float* x    = (const float*)d_in[0];
    const float* Wq   = (const float*)d_in[1];
    const float* Wk   = (const float*)d_in[2];
    const float* Wv   = (const float*)d_in[3];
    const float* cosp = (const float*)d_in[4];
    const float* sinp = (const float*)d_in[5];
    float* out = (float*)d_out;

    unsigned short* qws = (unsigned short*)d_ws;          // 16384*128 bf16 (4 MB)
    unsigned short* kws = qws + (size_t)M_ * HD_;         // 4 MB
    unsigned short* vws = kws + (size_t)M_ * HD_;         // (B,128,T) bf16, 4 MB
    unsigned short* wbf = vws + (size_t)M_ * HD_;         // [3][128][2048] bf16, 1.5 MB

    wconv<<<dim3(384), dim3(256), 0, stream>>>(Wq, Wk, Wv, wbf);
    qkv_gemm<<<dim3(768), dim3(256), 0, stream>>>(x, wbf, cosp, sinp, qws, kws, vws);
    attn<<<dim3(B_ * (T_ / 32)), dim3(256), 0, stream>>>(qws, kws, vws, out);
}